// Round 1
// baseline (1453.236 us; speedup 1.0000x reference)
//
#include <hip/hip_runtime.h>

#define BATCH 1024
#define SEQ   1024
#define FDIM  36
#define HID   20
#define G3    60
#define CR    64          // rows per LDS gi chunk
#define NCHUNK (SEQ/CR)   // 16

typedef float v2f __attribute__((ext_vector_type(2)));
typedef int   v2i __attribute__((ext_vector_type(2)));

__device__ __forceinline__ float fast_sigmoid(float x){
    return __builtin_amdgcn_rcpf(1.0f + __expf(-x));
}
__device__ __forceinline__ float fast_tanh(float x){
    return fmaf(-2.0f, __builtin_amdgcn_rcpf(1.0f + __expf(2.0f*x)), 1.0f);
}

#define READLANE_F(v, u) __int_as_float(__builtin_amdgcn_readlane(__float_as_int(v), (u)))

// Cross-half fetch: for lanes<32 returns s from lane+32. One VALU permlane
// (~10cy) replaces a ds_bpermute (~300cy single-outstanding). The (a+b)-s
// form is orientation-proof for either vdst/vsrc swap semantics; rounding
// error <= 1 ulp of the sum (irrelevant at 1e-3 tolerance).
__device__ __forceinline__ float upper_half_of(float s){
#if __has_builtin(__builtin_amdgcn_permlane32_swap)
    v2i pr = __builtin_amdgcn_permlane32_swap(__float_as_int(s), __float_as_int(s), false, false);
    return (__int_as_float(pr.x) + __int_as_float(pr.y)) - s;
#else
    float a = s, b = s;
    asm("v_permlane32_swap_b32 %0, %1" : "+v"(a), "+v"(b));
    return (a + b) - s;
#endif
}

// One block per batch element, 2 waves:
//  wave0 (consumer): encoder GRU then decoder GRU
//  wave1 (producer): embed/concat -> origin rows + gi = Wih1@x+bih1 into a
//                    double-buffered LDS chunk (64 steps). __syncthreads pipelines.
//
// R7 gate-lane relayout: unit u lives on lanes {u, 32+u}:
//   lane u      : kA = r-row u,    kB = n-row 40+u
//   lane 32+u   : kA = z-row 20+u, kB = dup
// One sigmoid computes r (lower) / z (upper); z reaches lane u via
// v_permlane32_swap (VALU) -- no ds_bpermute on the recurrence chain.
// Costs a 2nd Whh dot per lane: fine, per-SIMD issue occupancy is ~20%.
//
// R7 decoder: x broadcast via 36 v_readlane -> SGPRs (no LDS round-trip);
// decoder loop has zero DS ops.
//
// Register discipline (R6 lesson): decoder weights are loaded AFTER the chunk
// loop (live range must not span it). __launch_bounds__(128,2): 256-VGPR cap.
__global__ __launch_bounds__(128, 2)
void gru_fused(const float* __restrict__ x,
               const int* __restrict__ oh,
               const float* __restrict__ e0, const float* __restrict__ e1,
               const float* __restrict__ e2, const float* __restrict__ e3,
               const float* __restrict__ Wih1g, const float* __restrict__ Whh1g,
               const float* __restrict__ bih1g, const float* __restrict__ bhh1g,
               const float* __restrict__ Wih2g, const float* __restrict__ Whh2g,
               const float* __restrict__ bih2g, const float* __restrict__ bhh2g,
               const float* __restrict__ Wfcg,  const float* __restrict__ bfcg,
               float* __restrict__ origin, float* __restrict__ out2)
{
    __shared__ __align__(16) float gbuf[2][CR][G3];  // 30 KB gi double buffer
    __shared__ __align__(16) float psh[64];          // producer broadcast scratch

    const int lane   = threadIdx.x & 63;
    const bool is_enc = (threadIdx.x < 64);          // wave0 = consumer
    const int b = __builtin_amdgcn_readfirstlane(blockIdx.x);

    // ---- consumer gate-lane mapping (R7) ----
    const int ulr = lane & 31;
    const int ul  = ulr < HID ? ulr : HID - 1;             // dup lanes clamp to unit 19
    const int kA  = (lane < 32) ? ul : (HID + ul);         // r-row | z-row
    const int kB  = (lane < 32) ? (2 * HID + ul) : (HID + ul); // n-row | dup

    // ---- consumer cross-loop state (minimal: whh1 A/B + hs) ----
    float whh1A[HID], whh1B[HID];
    float bh1A = 0.f, bh1B = 0.f;
    float hs[HID];
    float hv = 0.0f;
    if (is_enc) {
        #pragma unroll
        for (int u = 0; u < HID; u++) whh1A[u] = Whh1g[kA * HID + u];
        #pragma unroll
        for (int u = 0; u < HID; u++) whh1B[u] = Whh1g[kB * HID + u];
        bh1A = bhh1g[kA];
        bh1B = bhh1g[kB];
        #pragma unroll
        for (int u = 0; u < HID; u++) hs[u] = 0.0f;
    }

    // ---- producer state (layout unchanged: gate-row k per lane) ----
    const int k = lane < G3 ? lane : G3 - 1;
    const int j = lane;
    const float* tbl; int ohc, eshift, sub;
    if (j < 16)      { tbl = e0; ohc = 0; eshift = 2; sub = j - 12; }
    else if (j < 20) { tbl = e1; ohc = 1; eshift = 2; sub = j - 16; }
    else if (j < 28) { tbl = e2; ohc = 2; eshift = 3; sub = j - 20; }
    else             { tbl = e3; ohc = 3; eshift = 3; sub = j - 28; }
    if (sub < 0) sub = 0;
    if (sub > 7) sub = 7;
    const bool from_x = (j < 12);
    const float* pa = from_x ? (x + j) : (tbl + sub);
    v2f w1p[FDIM/2]; float bi1 = 0.f;
    if (!is_enc) {
        #pragma unroll
        for (int q = 0; q < FDIM/2; q++) w1p[q] = ((const v2f*)(Wih1g + k * FDIM))[q];
        bi1 = bih1g[k];
    }

// Gate step, permlane form. Two Whh dots/lane; single shared sigmoid; one
// permlane32_swap; no ds_bpermute. Valid h only on lanes 0..19 (readlane'd).
#define GATE_STEP2(GIA, GIB, WA, WB, BA, BB, HVAR) do {                      \
        float a0 = (BA), a1 = 0.f, a2 = 0.f, a3 = 0.f;                       \
        float b0 = (BB), b1 = 0.f, b2 = 0.f, b3 = 0.f;                       \
        _Pragma("unroll")                                                    \
        for (int uu = 0; uu < HID; uu += 4) {                                \
            a0 = fmaf(WA[uu + 0], hs[uu + 0], a0);                           \
            a1 = fmaf(WA[uu + 1], hs[uu + 1], a1);                           \
            a2 = fmaf(WA[uu + 2], hs[uu + 2], a2);                           \
            a3 = fmaf(WA[uu + 3], hs[uu + 3], a3);                           \
            b0 = fmaf(WB[uu + 0], hs[uu + 0], b0);                           \
            b1 = fmaf(WB[uu + 1], hs[uu + 1], b1);                           \
            b2 = fmaf(WB[uu + 2], hs[uu + 2], b2);                           \
            b3 = fmaf(WB[uu + 3], hs[uu + 3], b3);                           \
        }                                                                    \
        float ghA = (a0 + a1) + (a2 + a3);                                   \
        float ghB = (b0 + b1) + (b2 + b3);                                   \
        float s_  = fast_sigmoid((GIA) + ghA);   /* r lower | z upper */     \
        float z_  = upper_half_of(s_);           /* z to lower lanes  */     \
        float n_  = fast_tanh(fmaf(s_, ghB, (GIB)));                         \
        HVAR = n_ + z_ * (HVAR - n_);                                        \
        _Pragma("unroll")                                                    \
        for (int uu = 0; uu < HID; uu++) hs[uu] = READLANE_F(HVAR, uu);      \
    } while (0)

#define CONSUME_CHUNK2(CB) do {                                              \
        const float* gpA = &gbuf[CB][0][0] + kA;                             \
        const float* gpB = &gbuf[CB][0][0] + kB;                             \
        float gA0 = gpA[0],  gB0 = gpB[0];                                   \
        float gA1 = gpA[G3], gB1 = gpB[G3];                                  \
        _Pragma("unroll 1")                                                  \
        for (int i = 0; i < CR; i += 2) {                                    \
            float eA = gA0, eB = gB0, oA = gA1, oB = gB1;                    \
            if (i < CR - 2) { gA0 = gpA[(i + 2) * G3]; gB0 = gpB[(i + 2) * G3]; } \
            GATE_STEP2(eA, eB, whh1A, whh1B, bh1A, bh1B, hv);                \
            if (i < CR - 2) { gA1 = gpA[(i + 3) * G3]; gB1 = gpB[(i + 3) * G3]; } \
            GATE_STEP2(oA, oB, whh1A, whh1B, bh1A, bh1B, hv);                \
        }                                                                    \
    } while (0)

    // ---------------- pipelined chunk loop ----------------
    #pragma unroll 1
    for (int c = 0; c < NCHUNK; ++c) {
        if (!is_enc) {
            const int rbase = b * SEQ + c * CR;
            float* gdst = &gbuf[c & 1][0][0];
            const float4* xp4 = (const float4*)psh;
            // R7 producer pipeline: oh prefetched 2 groups ahead, gathers 1
            // group ahead, so the oh->gather 2-level HBM chain hides under
            // the 8-row process body instead of serializing per group.
            int ohA[8], ohB[8]; float valA[8];
            #pragma unroll
            for (int n = 0; n < 8; n++) ohA[n] = oh[(rbase + n) * 4 + ohc];
            #pragma unroll
            for (int n = 0; n < 8; n++) ohB[n] = oh[(rbase + 8 + n) * 4 + ohc];
            #pragma unroll
            for (int n = 0; n < 8; n++) {
                int R = rbase + n;
                int off = from_x ? (R * 12) : (ohA[n] << eshift);
                valA[n] = pa[off];
            }
            #pragma unroll 1
            for (int g = 0; g < CR / 8; ++g) {
                int ohN[8]; float valB[8];
                if (g < 6) {
                    #pragma unroll
                    for (int n = 0; n < 8; n++)
                        ohN[n] = oh[(rbase + 8 * (g + 2) + n) * 4 + ohc];
                }
                if (g < 7) {
                    #pragma unroll
                    for (int n = 0; n < 8; n++) {
                        int R = rbase + 8 * (g + 1) + n;
                        int off = from_x ? (R * 12) : (ohB[n] << eshift);
                        valB[n] = pa[off];
                    }
                }
                #pragma unroll
                for (int n = 0; n < 8; n++) {
                    const int i = 8 * g + n;
                    const size_t R = (size_t)(rbase + i);
                    psh[lane] = valA[n];              // same-wave DS ordering
                    if (lane < FDIM) origin[R * FDIM + lane] = valA[n];
                    v2f a0 = {bi1, 0.f}, a1 = {0.f, 0.f};
                    #pragma unroll
                    for (int q = 0; q < 9; q++) {
                        float4 xv4 = xp4[q];
                        v2f xlo = {xv4.x, xv4.y}, xhi = {xv4.z, xv4.w};
                        a0 = __builtin_elementwise_fma(w1p[2*q],     xlo, a0);
                        a1 = __builtin_elementwise_fma(w1p[2*q + 1], xhi, a1);
                    }
                    float gg = (a0.x + a1.x) + (a0.y + a1.y);
                    if (lane < G3) gdst[i * G3 + lane] = gg;
                }
                if (g < 6) {
                    #pragma unroll
                    for (int n = 0; n < 8; n++) ohB[n] = ohN[n];
                }
                if (g < 7) {
                    #pragma unroll
                    for (int n = 0; n < 8; n++) valA[n] = valB[n];
                }
            }
        } else if (c > 0) {
            CONSUME_CHUNK2((c - 1) & 1);
        }
        __syncthreads();
    }
    if (!is_enc) return;              // producer done (after its final barrier)

    CONSUME_CHUNK2((NCHUNK - 1) & 1); // last chunk; no further barriers

    // ---- decoder weights loaded only now (live range does not span chunk loop) ----
    const int kf = lane < FDIM ? lane : FDIM - 1;
    float wihA[FDIM], wihB[FDIM];     // rows kA, kB of Wih2 (scalar, SGPR-x FMAs)
    float whh2A[HID], whh2B[HID], wfc[HID];
    #pragma unroll
    for (int q = 0; q < FDIM; q++) wihA[q] = Wih2g[kA * FDIM + q];
    #pragma unroll
    for (int q = 0; q < FDIM; q++) wihB[q] = Wih2g[kB * FDIM + q];
    #pragma unroll
    for (int u = 0; u < HID; u++) whh2A[u] = Whh2g[kA * HID + u];
    #pragma unroll
    for (int u = 0; u < HID; u++) whh2B[u] = Whh2g[kB * HID + u];
    #pragma unroll
    for (int u = 0; u < HID; u++) wfc[u] = Wfcg[kf * HID + u];
    const float biA  = bih2g[kA], biB  = bih2g[kB];
    const float bh2A = bhh2g[kA], bh2B = bhh2g[kB];
    const float bf   = bfcg[kf];

    // ---------------- handoff ----------------
    float hvd = fast_tanh(hv);
    #pragma unroll
    for (int u = 0; u < HID; u++) hs[u] = READLANE_F(hvd, u);

    float* orow = out2 + ((size_t)b * SEQ + (SEQ - 1)) * FDIM;

    float xv;
    {
        float f0 = bf, f1 = 0.f, f2 = 0.f, f3 = 0.f;
        #pragma unroll
        for (int u = 0; u < HID; u += 4) {
            f0 = fmaf(wfc[u + 0], hs[u + 0], f0);
            f1 = fmaf(wfc[u + 1], hs[u + 1], f1);
            f2 = fmaf(wfc[u + 2], hs[u + 2], f2);
            f3 = fmaf(wfc[u + 3], hs[u + 3], f3);
        }
        xv = fast_tanh((f0 + f1) + (f2 + f3));
    }
    if (lane < FDIM) orow[lane] = xv;

    // ---------------- decoder (permlane gates, readlane x-broadcast, no DS) ----
    #pragma unroll 1
    for (int d = 1; d < SEQ; ++d) {
        orow -= FDIM;
        // gi rows kA,kB: broadcast x via v_readlane (36 SGPRs, short-lived),
        // 6 accumulators per dot to keep the FMA chain 6 deep.
        float c0 = biA, c1 = 0.f, c2 = 0.f, c3 = 0.f, c4 = 0.f, c5 = 0.f;
        float e0_ = biB, e1_ = 0.f, e2_ = 0.f, e3_ = 0.f, e4_ = 0.f, e5_ = 0.f;
        #pragma unroll
        for (int q = 0; q < FDIM; q += 6) {
            float x0_ = READLANE_F(xv, q + 0);
            float x1_ = READLANE_F(xv, q + 1);
            float x2_ = READLANE_F(xv, q + 2);
            float x3_ = READLANE_F(xv, q + 3);
            float x4_ = READLANE_F(xv, q + 4);
            float x5_ = READLANE_F(xv, q + 5);
            c0  = fmaf(wihA[q + 0], x0_, c0);   e0_ = fmaf(wihB[q + 0], x0_, e0_);
            c1  = fmaf(wihA[q + 1], x1_, c1);   e1_ = fmaf(wihB[q + 1], x1_, e1_);
            c2  = fmaf(wihA[q + 2], x2_, c2);   e2_ = fmaf(wihB[q + 2], x2_, e2_);
            c3  = fmaf(wihA[q + 3], x3_, c3);   e3_ = fmaf(wihB[q + 3], x3_, e3_);
            c4  = fmaf(wihA[q + 4], x4_, c4);   e4_ = fmaf(wihB[q + 4], x4_, e4_);
            c5  = fmaf(wihA[q + 5], x5_, c5);   e5_ = fmaf(wihB[q + 5], x5_, e5_);
        }
        float giA = ((c0 + c1) + (c2 + c3)) + (c4 + c5);
        float giB = ((e0_ + e1_) + (e2_ + e3_)) + (e4_ + e5_);

        float a0 = bh2A, a1 = 0.f, a2 = 0.f, a3 = 0.f;
        float b0 = bh2B, b1 = 0.f, b2 = 0.f, b3 = 0.f;
        #pragma unroll
        for (int u = 0; u < HID; u += 4) {
            a0 = fmaf(whh2A[u + 0], hs[u + 0], a0);
            a1 = fmaf(whh2A[u + 1], hs[u + 1], a1);
            a2 = fmaf(whh2A[u + 2], hs[u + 2], a2);
            a3 = fmaf(whh2A[u + 3], hs[u + 3], a3);
            b0 = fmaf(whh2B[u + 0], hs[u + 0], b0);
            b1 = fmaf(whh2B[u + 1], hs[u + 1], b1);
            b2 = fmaf(whh2B[u + 2], hs[u + 2], b2);
            b3 = fmaf(whh2B[u + 3], hs[u + 3], b3);
        }
        float ghA = (a0 + a1) + (a2 + a3);
        float ghB = (b0 + b1) + (b2 + b3);

        float s_ = fast_sigmoid(giA + ghA);     // r lower | z upper
        float z_ = upper_half_of(s_);
        float n_ = fast_tanh(fmaf(s_, ghB, giB));
        hvd = fast_tanh(fmaf(z_, hvd - n_, n_));
        #pragma unroll
        for (int u = 0; u < HID; u++) hs[u] = READLANE_F(hvd, u);

        float f0 = bf, f1 = 0.f, f2 = 0.f, f3 = 0.f;
        #pragma unroll
        for (int u = 0; u < HID; u += 4) {
            f0 = fmaf(wfc[u + 0], hs[u + 0], f0);
            f1 = fmaf(wfc[u + 1], hs[u + 1], f1);
            f2 = fmaf(wfc[u + 2], hs[u + 2], f2);
            f3 = fmaf(wfc[u + 3], hs[u + 3], f3);
        }
        xv = fast_tanh((f0 + f1) + (f2 + f3));
        if (lane < FDIM) orow[lane] = xv;
    }
}

extern "C" void kernel_launch(void* const* d_in, const int* in_sizes, int n_in,
                              void* d_out, int out_size, void* d_ws, size_t ws_size,
                              hipStream_t stream) {
    const float* x    = (const float*)d_in[0];
    const int*   oh   = (const int*)d_in[1];
    const float* e0   = (const float*)d_in[2];
    const float* e1   = (const float*)d_in[3];
    const float* e2   = (const float*)d_in[4];
    const float* e3   = (const float*)d_in[5];
    const float* Wih1 = (const float*)d_in[6];
    const float* Whh1 = (const float*)d_in[7];
    const float* bih1 = (const float*)d_in[8];
    const float* bhh1 = (const float*)d_in[9];
    const float* Wih2 = (const float*)d_in[10];
    const float* Whh2 = (const float*)d_in[11];
    const float* bih2 = (const float*)d_in[12];
    const float* bhh2 = (const float*)d_in[13];
    const float* Wfc  = (const float*)d_in[14];
    const float* bfc  = (const float*)d_in[15];

    float* out    = (float*)d_out;
    float* origin = out;                                // output 0: (B,S,F)
    float* out2   = out + (size_t)BATCH * SEQ * FDIM;   // output 1: (B,S,F)

    gru_fused<<<BATCH, 128, 0, stream>>>(x, oh, e0, e1, e2, e3,
                                         Wih1, Whh1, bih1, bhh1,
                                         Wih2, Whh2, bih2, bhh2,
                                         Wfc, bfc, origin, out2);
}

// Round 2
// 1102.327 us; speedup vs baseline: 1.3183x; 1.3183x over previous
//
#include <hip/hip_runtime.h>

#define BATCH 1024
#define SEQ   1024
#define FDIM  36
#define HID   20
#define G3    60
#define CR    64          // rows per LDS gi chunk
#define NCHUNK (SEQ/CR)   // 16

typedef float v2f __attribute__((ext_vector_type(2)));
typedef int   v2i __attribute__((ext_vector_type(2)));

__device__ __forceinline__ float fast_sigmoid(float x){
    return __builtin_amdgcn_rcpf(1.0f + __expf(-x));
}
__device__ __forceinline__ float fast_tanh(float x){
    return fmaf(-2.0f, __builtin_amdgcn_rcpf(1.0f + __expf(2.0f*x)), 1.0f);
}

#define READLANE_F(v, u) __int_as_float(__builtin_amdgcn_readlane(__float_as_int(v), (u)))

// Cross-half fetch: lane i returns s from lane i^32. One VALU permlane pair
// (~10cy) instead of ds_bpermute (~100cy+ on the dependence chain). The
// (a+b)-s form is orientation-proof; error <= 1 ulp of the sum.
__device__ __forceinline__ float upper_half_of(float s){
#if __has_builtin(__builtin_amdgcn_permlane32_swap)
    v2i pr = __builtin_amdgcn_permlane32_swap(__float_as_int(s), __float_as_int(s), false, false);
    return (__int_as_float(pr.x) + __int_as_float(pr.y)) - s;
#else
    float a = s, b = s;
    asm("v_permlane32_swap_b32 %0, %1" : "+v"(a), "+v"(b));
    return (a + b) - s;
#endif
}

// One block per batch element, 2 waves:
//  wave0 (consumer): encoder GRU then decoder GRU
//  wave1 (producer): embed/concat -> origin rows + gi = Wih1@x+bih1 into a
//                    double-buffered LDS chunk (64 steps). __syncthreads pipelines.
//                    Producer is the R6-proven form (R7's pipelined producer and
//                    readlane x-broadcast are reverted: +524us regression).
//
// R8 gate-lane relayout (the only change vs the 751us kernel): unit u lives on
// lanes {u, 32+u}:
//   lane u    : kA = r-row u,    kB = n-row 40+u   (two dots)
//   lane 32+u : kA = z-row 20+u, kB = dup
// One shared sigmoid gives r (lower) / z (upper); z reaches lane u via
// v_permlane32_swap -- no ds_bpermute on the recurrence chain.
// Decoder x-broadcast stays on LDS dsh (R6 form).
// Register discipline (R6 lesson): decoder weights are loaded AFTER the chunk
// loop. __launch_bounds__(128,2): 256-VGPR cap -> no scratch spill.
__global__ __launch_bounds__(128, 2)
void gru_fused(const float* __restrict__ x,
               const int* __restrict__ oh,
               const float* __restrict__ e0, const float* __restrict__ e1,
               const float* __restrict__ e2, const float* __restrict__ e3,
               const float* __restrict__ Wih1g, const float* __restrict__ Whh1g,
               const float* __restrict__ bih1g, const float* __restrict__ bhh1g,
               const float* __restrict__ Wih2g, const float* __restrict__ Whh2g,
               const float* __restrict__ bih2g, const float* __restrict__ bhh2g,
               const float* __restrict__ Wfcg,  const float* __restrict__ bfcg,
               float* __restrict__ origin, float* __restrict__ out2)
{
    __shared__ __align__(16) float gbuf[2][CR][G3];  // 30 KB gi double buffer
    __shared__ __align__(16) float psh[64];          // producer broadcast scratch
    __shared__ __align__(16) float dsh[64];          // decoder x broadcast

    const int lane   = threadIdx.x & 63;
    const bool is_enc = (threadIdx.x < 64);          // wave0 = consumer
    const int b = __builtin_amdgcn_readfirstlane(blockIdx.x);

    // ---- consumer gate-lane mapping (R8) ----
    const int ulr = lane & 31;
    const int ul  = ulr < HID ? ulr : HID - 1;                 // dup lanes clamp
    const int kA  = (lane < 32) ? ul : (HID + ul);             // r-row | z-row
    const int kB  = (lane < 32) ? (2 * HID + ul) : (HID + ul); // n-row | dup

    // ---- consumer cross-loop state (minimal: whh1 A/B + hs) ----
    float whh1A[HID], whh1B[HID];
    float bh1A = 0.f, bh1B = 0.f;
    float hs[HID];
    float hv = 0.0f;
    if (is_enc) {
        #pragma unroll
        for (int u = 0; u < HID; u++) whh1A[u] = Whh1g[kA * HID + u];
        #pragma unroll
        for (int u = 0; u < HID; u++) whh1B[u] = Whh1g[kB * HID + u];
        bh1A = bhh1g[kA];
        bh1B = bhh1g[kB];
        #pragma unroll
        for (int u = 0; u < HID; u++) hs[u] = 0.0f;
    }

    // ---- producer state (R6-proven, unchanged) ----
    const int k = lane < G3 ? lane : G3 - 1;
    const int j = lane;
    const float* tbl; int ohc, eshift, sub;
    if (j < 16)      { tbl = e0; ohc = 0; eshift = 2; sub = j - 12; }
    else if (j < 20) { tbl = e1; ohc = 1; eshift = 2; sub = j - 16; }
    else if (j < 28) { tbl = e2; ohc = 2; eshift = 3; sub = j - 20; }
    else             { tbl = e3; ohc = 3; eshift = 3; sub = j - 28; }
    if (sub < 0) sub = 0;
    if (sub > 7) sub = 7;
    const bool from_x = (j < 12);
    const float* pa = from_x ? (x + j) : (tbl + sub);
    v2f w1p[FDIM/2]; float bi1 = 0.f;
    if (!is_enc) {
        #pragma unroll
        for (int q = 0; q < FDIM/2; q++) w1p[q] = ((const v2f*)(Wih1g + k * FDIM))[q];
        bi1 = bih1g[k];
    }

// Gate step, permlane form. Two Whh dots/lane; single shared sigmoid; one
// permlane32_swap; no ds_bpermute. Valid h only on lanes 0..19 (readlane'd).
#define GATE_STEP2(GIA, GIB, WA, WB, BA, BB, HVAR) do {                      \
        float a0 = (BA), a1 = 0.f, a2 = 0.f, a3 = 0.f;                       \
        float b0 = (BB), b1 = 0.f, b2 = 0.f, b3 = 0.f;                       \
        _Pragma("unroll")                                                    \
        for (int uu = 0; uu < HID; uu += 4) {                                \
            a0 = fmaf(WA[uu + 0], hs[uu + 0], a0);                           \
            a1 = fmaf(WA[uu + 1], hs[uu + 1], a1);                           \
            a2 = fmaf(WA[uu + 2], hs[uu + 2], a2);                           \
            a3 = fmaf(WA[uu + 3], hs[uu + 3], a3);                           \
            b0 = fmaf(WB[uu + 0], hs[uu + 0], b0);                           \
            b1 = fmaf(WB[uu + 1], hs[uu + 1], b1);                           \
            b2 = fmaf(WB[uu + 2], hs[uu + 2], b2);                           \
            b3 = fmaf(WB[uu + 3], hs[uu + 3], b3);                           \
        }                                                                    \
        float ghA = (a0 + a1) + (a2 + a3);                                   \
        float ghB = (b0 + b1) + (b2 + b3);                                   \
        float s_  = fast_sigmoid((GIA) + ghA);   /* r lower | z upper */     \
        float z_  = upper_half_of(s_);           /* z to lower lanes  */     \
        float n_  = fast_tanh(fmaf(s_, ghB, (GIB)));                         \
        HVAR = fmaf(z_, HVAR - n_, n_);                                      \
        _Pragma("unroll")                                                    \
        for (int uu = 0; uu < HID; uu++) hs[uu] = READLANE_F(HVAR, uu);      \
    } while (0)

#define CONSUME_CHUNK2(CB) do {                                              \
        const float* gpA = &gbuf[CB][0][0] + kA;                             \
        const float* gpB = &gbuf[CB][0][0] + kB;                             \
        float gA0 = gpA[0],  gB0 = gpB[0];                                   \
        float gA1 = gpA[G3], gB1 = gpB[G3];                                  \
        _Pragma("unroll 1")                                                  \
        for (int i = 0; i < CR; i += 2) {                                    \
            float eA = gA0, eB = gB0, oA = gA1, oB = gB1;                    \
            if (i < CR - 2) { gA0 = gpA[(i + 2) * G3]; gB0 = gpB[(i + 2) * G3]; } \
            GATE_STEP2(eA, eB, whh1A, whh1B, bh1A, bh1B, hv);                \
            if (i < CR - 2) { gA1 = gpA[(i + 3) * G3]; gB1 = gpB[(i + 3) * G3]; } \
            GATE_STEP2(oA, oB, whh1A, whh1B, bh1A, bh1B, hv);                \
        }                                                                    \
    } while (0)

    // ---------------- pipelined chunk loop ----------------
    #pragma unroll 1
    for (int c = 0; c < NCHUNK; ++c) {
        if (!is_enc) {
            const int rbase = b * SEQ + c * CR;
            float* gdst = &gbuf[c & 1][0][0];
            const float4* xp4 = (const float4*)psh;
            #pragma unroll 1
            for (int g = 0; g < CR / 8; ++g) {
                int ohv[8];
                #pragma unroll
                for (int n = 0; n < 8; n++)
                    ohv[n] = oh[(rbase + 8 * g + n) * 4 + ohc];
                float valv[8];
                #pragma unroll
                for (int n = 0; n < 8; n++) {
                    int R = rbase + 8 * g + n;
                    int off = from_x ? (R * 12) : (ohv[n] << eshift);
                    valv[n] = pa[off];
                }
                #pragma unroll
                for (int n = 0; n < 8; n++) {
                    const int i = 8 * g + n;
                    const size_t R = (size_t)(rbase + i);
                    psh[lane] = valv[n];              // same-wave DS ordering
                    if (lane < FDIM) origin[R * FDIM + lane] = valv[n];
                    v2f a0 = {bi1, 0.f}, a1 = {0.f, 0.f};
                    #pragma unroll
                    for (int q = 0; q < 9; q++) {
                        float4 xv4 = xp4[q];
                        v2f xlo = {xv4.x, xv4.y}, xhi = {xv4.z, xv4.w};
                        a0 = __builtin_elementwise_fma(w1p[2*q],     xlo, a0);
                        a1 = __builtin_elementwise_fma(w1p[2*q + 1], xhi, a1);
                    }
                    float gg = (a0.x + a1.x) + (a0.y + a1.y);
                    if (lane < G3) gdst[i * G3 + lane] = gg;
                }
            }
        } else if (c > 0) {
            CONSUME_CHUNK2((c - 1) & 1);
        }
        __syncthreads();
    }
    if (!is_enc) return;              // producer done (after its final barrier)

    CONSUME_CHUNK2((NCHUNK - 1) & 1); // last chunk; no further barriers

    // ---- decoder weights loaded only now (live range does not span chunk loop) ----
    const int kf = lane < FDIM ? lane : FDIM - 1;
    v2f wihA[FDIM/2], wihB[FDIM/2];   // Wih2 rows kA, kB
    float whh2A[HID], whh2B[HID], wfc[HID];
    #pragma unroll
    for (int q = 0; q < FDIM/2; q++) wihA[q] = ((const v2f*)(Wih2g + kA * FDIM))[q];
    #pragma unroll
    for (int q = 0; q < FDIM/2; q++) wihB[q] = ((const v2f*)(Wih2g + kB * FDIM))[q];
    #pragma unroll
    for (int u = 0; u < HID; u++) whh2A[u] = Whh2g[kA * HID + u];
    #pragma unroll
    for (int u = 0; u < HID; u++) whh2B[u] = Whh2g[kB * HID + u];
    #pragma unroll
    for (int u = 0; u < HID; u++) wfc[u] = Wfcg[kf * HID + u];
    const float biA  = bih2g[kA], biB  = bih2g[kB];
    const float bh2A = bhh2g[kA], bh2B = bhh2g[kB];
    const float bf   = bfcg[kf];

    // ---------------- handoff ----------------
    float hvd = fast_tanh(hv);
    #pragma unroll
    for (int u = 0; u < HID; u++) hs[u] = READLANE_F(hvd, u);

    float* orow = out2 + ((size_t)b * SEQ + (SEQ - 1)) * FDIM;

    float xv;
    {
        float f0 = bf, f1 = 0.f, f2 = 0.f, f3 = 0.f;
        #pragma unroll
        for (int u = 0; u < HID; u += 4) {
            f0 = fmaf(wfc[u + 0], hs[u + 0], f0);
            f1 = fmaf(wfc[u + 1], hs[u + 1], f1);
            f2 = fmaf(wfc[u + 2], hs[u + 2], f2);
            f3 = fmaf(wfc[u + 3], hs[u + 3], f3);
        }
        xv = fast_tanh((f0 + f1) + (f2 + f3));
    }
    dsh[lane] = xv;                   // intra-wave broadcast (same wave)
    if (lane < FDIM) orow[lane] = xv;

    // ---------------- decoder (permlane gates, LDS x-broadcast, R6 skeleton) ----
    const v2f* xp = (const v2f*)dsh;
    #pragma unroll 1
    for (int d = 1; d < SEQ; ++d) {
        orow -= FDIM;
        v2f xs2[FDIM/2];
        #pragma unroll
        for (int q = 0; q < FDIM/2; q++) xs2[q] = xp[q];

        float a0 = bh2A, a1 = 0.f, a2 = 0.f, a3 = 0.f;
        float b0 = bh2B, b1 = 0.f, b2 = 0.f, b3 = 0.f;
        #pragma unroll
        for (int u = 0; u < HID; u += 4) {
            a0 = fmaf(whh2A[u + 0], hs[u + 0], a0);
            a1 = fmaf(whh2A[u + 1], hs[u + 1], a1);
            a2 = fmaf(whh2A[u + 2], hs[u + 2], a2);
            a3 = fmaf(whh2A[u + 3], hs[u + 3], a3);
            b0 = fmaf(whh2B[u + 0], hs[u + 0], b0);
            b1 = fmaf(whh2B[u + 1], hs[u + 1], b1);
            b2 = fmaf(whh2B[u + 2], hs[u + 2], b2);
            b3 = fmaf(whh2B[u + 3], hs[u + 3], b3);
        }
        float ghA = (a0 + a1) + (a2 + a3);
        float ghB = (b0 + b1) + (b2 + b3);

        v2f cA0 = {biA, 0.f}, cA1 = {0.f, 0.f};
        v2f cB0 = {biB, 0.f}, cB1 = {0.f, 0.f};
        #pragma unroll
        for (int q = 0; q < FDIM/2; q += 2) {
            cA0 = __builtin_elementwise_fma(wihA[q],     xs2[q],     cA0);
            cA1 = __builtin_elementwise_fma(wihA[q + 1], xs2[q + 1], cA1);
            cB0 = __builtin_elementwise_fma(wihB[q],     xs2[q],     cB0);
            cB1 = __builtin_elementwise_fma(wihB[q + 1], xs2[q + 1], cB1);
        }
        float giA = (cA0.x + cA1.x) + (cA0.y + cA1.y);
        float giB = (cB0.x + cB1.x) + (cB0.y + cB1.y);

        float s_ = fast_sigmoid(giA + ghA);     // r lower | z upper
        float z_ = upper_half_of(s_);
        float n_ = fast_tanh(fmaf(s_, ghB, giB));
        hvd = fast_tanh(fmaf(z_, hvd - n_, n_));
        #pragma unroll
        for (int u = 0; u < HID; u++) hs[u] = READLANE_F(hvd, u);

        float f0 = bf, f1 = 0.f, f2 = 0.f, f3 = 0.f;
        #pragma unroll
        for (int u = 0; u < HID; u += 4) {
            f0 = fmaf(wfc[u + 0], hs[u + 0], f0);
            f1 = fmaf(wfc[u + 1], hs[u + 1], f1);
            f2 = fmaf(wfc[u + 2], hs[u + 2], f2);
            f3 = fmaf(wfc[u + 3], hs[u + 3], f3);
        }
        xv = fast_tanh((f0 + f1) + (f2 + f3));
        dsh[lane] = xv;               // LDS write issued before the global store
        if (lane < FDIM) orow[lane] = xv;
    }
}

extern "C" void kernel_launch(void* const* d_in, const int* in_sizes, int n_in,
                              void* d_out, int out_size, void* d_ws, size_t ws_size,
                              hipStream_t stream) {
    const float* x    = (const float*)d_in[0];
    const int*   oh   = (const int*)d_in[1];
    const float* e0   = (const float*)d_in[2];
    const float* e1   = (const float*)d_in[3];
    const float* e2   = (const float*)d_in[4];
    const float* e3   = (const float*)d_in[5];
    const float* Wih1 = (const float*)d_in[6];
    const float* Whh1 = (const float*)d_in[7];
    const float* bih1 = (const float*)d_in[8];
    const float* bhh1 = (const float*)d_in[9];
    const float* Wih2 = (const float*)d_in[10];
    const float* Whh2 = (const float*)d_in[11];
    const float* bih2 = (const float*)d_in[12];
    const float* bhh2 = (const float*)d_in[13];
    const float* Wfc  = (const float*)d_in[14];
    const float* bfc  = (const float*)d_in[15];

    float* out    = (float*)d_out;
    float* origin = out;                                // output 0: (B,S,F)
    float* out2   = out + (size_t)BATCH * SEQ * FDIM;   // output 1: (B,S,F)

    gru_fused<<<BATCH, 128, 0, stream>>>(x, oh, e0, e1, e2, e3,
                                         Wih1, Whh1, bih1, bhh1,
                                         Wih2, Whh2, bih2, bhh2,
                                         Wfc, bfc, origin, out2);
}

// Round 3
// 988.688 us; speedup vs baseline: 1.4699x; 1.1149x over previous
//
#include <hip/hip_runtime.h>

#define BATCH 1024
#define SEQ   1024
#define FDIM  36
#define HID   20
#define G3    60
#define CR    64          // rows per LDS gi chunk
#define NCHUNK (SEQ/CR)   // 16

typedef float v2f __attribute__((ext_vector_type(2)));

__device__ __forceinline__ float fast_sigmoid(float x){
    return __builtin_amdgcn_rcpf(1.0f + __expf(-x));
}
__device__ __forceinline__ float fast_tanh(float x){
    return fmaf(-2.0f, __builtin_amdgcn_rcpf(1.0f + __expf(2.0f*x)), 1.0f);
}

#define READLANE_F(v, u) __int_as_float(__builtin_amdgcn_readlane(__float_as_int(v), (u)))

// One block per batch element, 2 waves:
//  wave0 (consumer): encoder GRU then decoder GRU (R3-proven gate-row-major form)
//  wave1 (producer): embed/concat -> origin rows + gi = Wih1@x+bih1 into a
//                    double-buffered LDS chunk (64 steps). __syncthreads pipelines.
// gi never touches HBM. Producer has ~3x slack vs consumer.
//
// R8 lesson (measured): permlane gate relayout (2 dots/lane, no bpermute) is
// +143cy/step NET LOSS -- extra wave64 issue outweighs bpermute latency. The
// R6 single-dot + 3-bpermute form is kept.
//
// R9 (this round): decoder memory-latency surgery, zero extra arithmetic:
//  (a) unroll x2 with alternating store regs xvA/xvB -- the out2 store's
//      vmcnt drain (store-data reg redefinition) moves 2 steps away instead
//      of gating every step (decoder phase is 1 wave/SIMD: drains are naked).
//  (b) pre-issue next step's 9 ds_read_b128 of dsh right after the ds_write
//      (same-wave DS ordering) so LDS read latency hides under store+gh dot.
// Per-step math is bit-identical to the 751us R6 kernel.
//
// Register discipline (R6 lesson): decoder weights are loaded AFTER the chunk
// loop (live range must not span it). __launch_bounds__(128,2): 256-VGPR cap.
__global__ __launch_bounds__(128, 2)
void gru_fused(const float* __restrict__ x,
               const int* __restrict__ oh,
               const float* __restrict__ e0, const float* __restrict__ e1,
               const float* __restrict__ e2, const float* __restrict__ e3,
               const float* __restrict__ Wih1g, const float* __restrict__ Whh1g,
               const float* __restrict__ bih1g, const float* __restrict__ bhh1g,
               const float* __restrict__ Wih2g, const float* __restrict__ Whh2g,
               const float* __restrict__ bih2g, const float* __restrict__ bhh2g,
               const float* __restrict__ Wfcg,  const float* __restrict__ bfcg,
               float* __restrict__ origin, float* __restrict__ out2)
{
    __shared__ __align__(16) float gbuf[2][CR][G3];  // 30 KB gi double buffer
    __shared__ __align__(16) float psh[64];          // producer broadcast scratch
    __shared__ __align__(16) float dsh[64];          // decoder x broadcast

    const int lane   = threadIdx.x & 63;
    const bool is_enc = (threadIdx.x < 64);          // wave0 = consumer
    const int b = __builtin_amdgcn_readfirstlane(blockIdx.x);

    const int k = lane < G3 ? lane : G3 - 1;

    // ---- consumer cross-loop state (kept minimal: whh1 + hs only) ----
    float whh1[HID];
    float bh1 = 0.f;
    float hs[HID];
    float hv = 0.0f;
    if (is_enc) {
        #pragma unroll
        for (int u = 0; u < HID; u++) whh1[u] = Whh1g[k * HID + u];
        bh1 = bhh1g[k];
        #pragma unroll
        for (int u = 0; u < HID; u++) hs[u] = 0.0f;
    }

    // ---- producer state ----
    const int j = lane;
    const float* tbl; int ohc, eshift, sub;
    if (j < 16)      { tbl = e0; ohc = 0; eshift = 2; sub = j - 12; }
    else if (j < 20) { tbl = e1; ohc = 1; eshift = 2; sub = j - 16; }
    else if (j < 28) { tbl = e2; ohc = 2; eshift = 3; sub = j - 20; }
    else             { tbl = e3; ohc = 3; eshift = 3; sub = j - 28; }
    if (sub < 0) sub = 0;
    if (sub > 7) sub = 7;
    const bool from_x = (j < 12);
    const float* pa = from_x ? (x + j) : (tbl + sub);
    v2f w1p[FDIM/2]; float bi1 = 0.f;
    if (!is_enc) {
        #pragma unroll
        for (int q = 0; q < FDIM/2; q++) w1p[q] = ((const v2f*)(Wih1g + k * FDIM))[q];
        bi1 = bih1g[k];
    }

#define GATE_STEP(GIV, WHH, BH, HVAR) do {                                   \
        float h0 = BH, h1 = 0.f, h2 = 0.f, h3 = 0.f;                         \
        _Pragma("unroll")                                                    \
        for (int uu = 0; uu < HID; uu += 4) {                                \
            h0 = fmaf(WHH[uu + 0], hs[uu + 0], h0);                          \
            h1 = fmaf(WHH[uu + 1], hs[uu + 1], h1);                          \
            h2 = fmaf(WHH[uu + 2], hs[uu + 2], h2);                          \
            h3 = fmaf(WHH[uu + 3], hs[uu + 3], h3);                          \
        }                                                                    \
        float gh = (h0 + h1) + (h2 + h3);                                    \
        float v   = (GIV) + gh;                                              \
        float vz  = __shfl(v,    (lane + 20) & 63);                          \
        float in_ = __shfl((GIV),(lane + 40) & 63);                          \
        float hn  = __shfl(gh,   (lane + 40) & 63);                          \
        float r = fast_sigmoid(v);                                           \
        float z = fast_sigmoid(vz);                                          \
        float n = fast_tanh(fmaf(r, hn, in_));                               \
        HVAR = n + z * (HVAR - n);                                           \
        _Pragma("unroll")                                                    \
        for (int uu = 0; uu < HID; uu++) hs[uu] = READLANE_F(HVAR, uu);      \
    } while (0)

#define CONSUME_CHUNK(CB) do {                                               \
        const float* gp = &gbuf[CB][0][k];                                   \
        float ga = gp[0], gbv = gp[G3];                                      \
        _Pragma("unroll 1")                                                  \
        for (int i = 0; i < CR; i += 2) {                                    \
            float ge = ga, go = gbv;                                         \
            if (i < CR - 2) ga = gp[(i + 2) * G3];                           \
            GATE_STEP(ge, whh1, bh1, hv);                                    \
            if (i < CR - 2) gbv = gp[(i + 3) * G3];                          \
            GATE_STEP(go, whh1, bh1, hv);                                    \
        }                                                                    \
    } while (0)

    // ---------------- pipelined chunk loop ----------------
    #pragma unroll 1
    for (int c = 0; c < NCHUNK; ++c) {
        if (!is_enc) {
            const int rbase = b * SEQ + c * CR;
            float* gdst = &gbuf[c & 1][0][0];
            const float4* xp4 = (const float4*)psh;
            #pragma unroll 1
            for (int g = 0; g < CR / 8; ++g) {
                int ohv[8];
                #pragma unroll
                for (int n = 0; n < 8; n++)
                    ohv[n] = oh[(rbase + 8 * g + n) * 4 + ohc];
                float valv[8];
                #pragma unroll
                for (int n = 0; n < 8; n++) {
                    int R = rbase + 8 * g + n;
                    int off = from_x ? (R * 12) : (ohv[n] << eshift);
                    valv[n] = pa[off];
                }
                #pragma unroll
                for (int n = 0; n < 8; n++) {
                    const int i = 8 * g + n;
                    const size_t R = (size_t)(rbase + i);
                    psh[lane] = valv[n];              // same-wave DS ordering
                    if (lane < FDIM) origin[R * FDIM + lane] = valv[n];
                    v2f a0 = {bi1, 0.f}, a1 = {0.f, 0.f};
                    #pragma unroll
                    for (int q = 0; q < 9; q++) {
                        float4 xv4 = xp4[q];
                        v2f xlo = {xv4.x, xv4.y}, xhi = {xv4.z, xv4.w};
                        a0 = __builtin_elementwise_fma(w1p[2*q],     xlo, a0);
                        a1 = __builtin_elementwise_fma(w1p[2*q + 1], xhi, a1);
                    }
                    float gg = (a0.x + a1.x) + (a0.y + a1.y);
                    if (lane < G3) gdst[i * G3 + lane] = gg;
                }
            }
        } else if (c > 0) {
            CONSUME_CHUNK((c - 1) & 1);
        }
        __syncthreads();
    }
    if (!is_enc) return;              // producer done (after its final barrier)

    CONSUME_CHUNK((NCHUNK - 1) & 1);  // last chunk; no further barriers

    // ---- decoder weights loaded only now (live range does not span chunk loop) ----
    const int kf = lane < FDIM ? lane : FDIM - 1;
    float whh2[HID], wfc[HID];
    v2f wih2p[FDIM/2];
    #pragma unroll
    for (int q = 0; q < FDIM/2; q++) wih2p[q] = ((const v2f*)(Wih2g + k * FDIM))[q];
    #pragma unroll
    for (int u = 0; u < HID; u++) whh2[u] = Whh2g[k * HID + u];
    #pragma unroll
    for (int u = 0; u < HID; u++) wfc[u] = Wfcg[kf * HID + u];
    const float bi2 = bih2g[k], bh2 = bhh2g[k];
    const float bf  = bfcg[kf];

    // ---------------- handoff ----------------
    float hvd = fast_tanh(hv);
    #pragma unroll
    for (int u = 0; u < HID; u++) hs[u] = READLANE_F(hvd, u);

    float* orow = out2 + ((size_t)b * SEQ + (SEQ - 1)) * FDIM;
    const v2f* xp = (const v2f*)dsh;

    float xv0;
    {
        float f0 = bf, f1 = 0.f, f2 = 0.f, f3 = 0.f;
        #pragma unroll
        for (int u = 0; u < HID; u += 4) {
            f0 = fmaf(wfc[u + 0], hs[u + 0], f0);
            f1 = fmaf(wfc[u + 1], hs[u + 1], f1);
            f2 = fmaf(wfc[u + 2], hs[u + 2], f2);
            f3 = fmaf(wfc[u + 3], hs[u + 3], f3);
        }
        xv0 = fast_tanh((f0 + f1) + (f2 + f3));
    }
    dsh[lane] = xv0;                  // intra-wave broadcast (same wave)
    // pre-issue step-1 x reads (same-wave DS ordering: safe, no barrier)
    v2f xsA[FDIM/2], xsB[FDIM/2];
    #pragma unroll
    for (int q = 0; q < FDIM/2; q++) xsA[q] = xp[q];
    if (lane < FDIM) orow[lane] = xv0;

// One decoder step, bit-identical math to R6. XSIN: pre-loaded x regs for this
// step. XSOUT: regs to pre-issue next step's dsh reads into. XST: the store
// register for this step (alternates A/B so the out2 store's vmcnt drain is
// 2 steps away, not 1).
#define DEC_STEP(XSIN, XSOUT, XST) do {                                      \
        float h0 = bh2, h1 = 0.f, h2 = 0.f, h3 = 0.f;                        \
        _Pragma("unroll")                                                    \
        for (int u = 0; u < HID; u += 4) {                                   \
            h0 = fmaf(whh2[u + 0], hs[u + 0], h0);                           \
            h1 = fmaf(whh2[u + 1], hs[u + 1], h1);                           \
            h2 = fmaf(whh2[u + 2], hs[u + 2], h2);                           \
            h3 = fmaf(whh2[u + 3], hs[u + 3], h3);                           \
        }                                                                    \
        float gh = (h0 + h1) + (h2 + h3);                                    \
        v2f accA = {bi2, 0.f}, accB = {0.f, 0.f};                            \
        _Pragma("unroll")                                                    \
        for (int q = 0; q < FDIM/2; q += 2) {                                \
            accA = __builtin_elementwise_fma(wih2p[q],     XSIN[q],     accA); \
            accB = __builtin_elementwise_fma(wih2p[q + 1], XSIN[q + 1], accB); \
        }                                                                    \
        float gi = (accA.x + accB.x) + (accA.y + accB.y);                    \
        float v   = gi + gh;                                                 \
        float vz  = __shfl(v,  (lane + 20) & 63);                            \
        float in_ = __shfl(gi, (lane + 40) & 63);                            \
        float hn  = __shfl(gh, (lane + 40) & 63);                            \
        float r = fast_sigmoid(v);                                           \
        float z = fast_sigmoid(vz);                                          \
        float n = fast_tanh(fmaf(r, hn, in_));                               \
        float hraw = n + z * (hvd - n);                                      \
        hvd = fast_tanh(hraw);                                               \
        _Pragma("unroll")                                                    \
        for (int u = 0; u < HID; u++) hs[u] = READLANE_F(hvd, u);            \
        float f0 = bf, f1 = 0.f, f2 = 0.f, f3 = 0.f;                         \
        _Pragma("unroll")                                                    \
        for (int u = 0; u < HID; u += 4) {                                   \
            f0 = fmaf(wfc[u + 0], hs[u + 0], f0);                            \
            f1 = fmaf(wfc[u + 1], hs[u + 1], f1);                            \
            f2 = fmaf(wfc[u + 2], hs[u + 2], f2);                            \
            f3 = fmaf(wfc[u + 3], hs[u + 3], f3);                            \
        }                                                                    \
        XST = fast_tanh((f0 + f1) + (f2 + f3));                              \
        orow -= FDIM;                                                        \
        dsh[lane] = XST;              /* write x, then immediately ... */    \
        _Pragma("unroll")                                                    \
        for (int q = 0; q < FDIM/2; q++) XSOUT[q] = xp[q]; /* pre-issue */   \
        if (lane < FDIM) orow[lane] = XST;                                   \
    } while (0)

    // ---------------- decoder: 511 unrolled pairs + 1 peeled = 1023 steps ----
    float xvA, xvB;
    #pragma unroll 1
    for (int i = 0; i < (SEQ - 2) / 2; ++i) {
        DEC_STEP(xsA, xsB, xvA);
        DEC_STEP(xsB, xsA, xvB);
    }
    DEC_STEP(xsA, xsB, xvA);          // final step (its XSOUT pre-issue is dead, harmless)
}

extern "C" void kernel_launch(void* const* d_in, const int* in_sizes, int n_in,
                              void* d_out, int out_size, void* d_ws, size_t ws_size,
                              hipStream_t stream) {
    const float* x    = (const float*)d_in[0];
    const int*   oh   = (const int*)d_in[1];
    const float* e0   = (const float*)d_in[2];
    const float* e1   = (const float*)d_in[3];
    const float* e2   = (const float*)d_in[4];
    const float* e3   = (const float*)d_in[5];
    const float* Wih1 = (const float*)d_in[6];
    const float* Whh1 = (const float*)d_in[7];
    const float* bih1 = (const float*)d_in[8];
    const float* bhh1 = (const float*)d_in[9];
    const float* Wih2 = (const float*)d_in[10];
    const float* Whh2 = (const float*)d_in[11];
    const float* bih2 = (const float*)d_in[12];
    const float* bhh2 = (const float*)d_in[13];
    const float* Wfc  = (const float*)d_in[14];
    const float* bfc  = (const float*)d_in[15];

    float* out    = (float*)d_out;
    float* origin = out;                                // output 0: (B,S,F)
    float* out2   = out + (size_t)BATCH * SEQ * FDIM;   // output 1: (B,S,F)

    gru_fused<<<BATCH, 128, 0, stream>>>(x, oh, e0, e1, e2, e3,
                                         Wih1, Whh1, bih1, bhh1,
                                         Wih2, Whh2, bih2, bhh2,
                                         Wfc, bfc, origin, out2);
}